// Round 8
// baseline (592.496 us; speedup 1.0000x reference)
//
#include <hip/hip_runtime.h>
#include <hip/hip_cooperative_groups.h>
#include <stdint.h>

namespace cg = cooperative_groups;

#define N_TOTAL 21840
#define NA      21888          // N_TOTAL rounded up to multiple of 64
#define W_MAX   342            // ceil(21840/64)
#define TOT_ENT 3753792u       // 64 * (342*343/2)  triangular CSR capacity
#define NMS_TH  0.3f
#define FINAL_TH 0.5f
#define NSLICE  8              // rank range-split factor
#define SLICE_N 2730           // N_TOTAL / NSLICE (exact)
#define GBLK    256
#define GTHR    1024

struct Inputs { const float* cls[6]; const float* reg[6]; };

// Raw barrier: drains LDS (lgkmcnt) but NOT vmem — prefetched global loads
// stay in flight. Valid when barriers order LDS state only (true in scan).
__device__ __forceinline__ void block_bar() {
  asm volatile("s_waitcnt lgkmcnt(0)\n\ts_barrier" ::: "memory");
}

// Closed-form CSR row base: row r (sorted pos) owns 342-(r>>6) slots.
__device__ __forceinline__ unsigned rowbase_u(unsigned r) {
  unsigned w = r >> 6, l = r & 63u;
  return 64u * (342u * w - (w * (w - 1u)) / 2u) + l * (342u - w);
}

// VALU-speed cross-lane reads (index wave-uniform).
__device__ __forceinline__ float rl_f(float x, int i) {
  return __int_as_float(__builtin_amdgcn_readlane(__float_as_int(x), i));
}
__device__ __forceinline__ unsigned long long rl_u64(unsigned long long x, int i) {
  unsigned lo = (unsigned)__builtin_amdgcn_readlane((int)(unsigned)(x & 0xffffffffull), i);
  unsigned hi = (unsigned)__builtin_amdgcn_readlane((int)(unsigned)(x >> 32), i);
  return ((unsigned long long)hi << 32) | lo;
}

// Per-wave sum of blockCnt[0..255] (uniform result in all lanes).
__device__ __forceinline__ int wave_sum_M(const unsigned int* blockCnt) {
  int l = (int)(threadIdx.x & 63);
  const uint4* p4 = (const uint4*)blockCnt;   // 64 x uint4 = 256 ints
  uint4 v = p4[l];
  int s = (int)(v.x + v.y + v.z + v.w);
#pragma unroll
  for (int off = 32; off; off >>= 1) s += __shfl_xor(s, off);
  return s;
}

struct Params {
  Inputs in;
  float *dx1, *dy1, *dx2, *dy2, *dsc;
  unsigned long long* ckey;
  unsigned int *rank32, *cnt, *blockCnt;
  float *sx1, *sy1, *sx2, *sy2;
  unsigned int* sorig;
  unsigned long long *diag, *offd;
  unsigned short* rlJw;
  unsigned long long* rlBits;
  float* out;
};

// =================== fused cooperative kernel (single node) =================
__global__ void __launch_bounds__(GTHR, 4)
fused_kernel(Params P) {
#pragma clang fp contract(off)
  __shared__ unsigned long long sup[W_MAX];
  __shared__ unsigned long long kmls[W_MAX];
  __shared__ int redsh[16];

  const int tid  = (int)threadIdx.x;
  const int bid  = (int)blockIdx.x;
  const int wav  = tid >> 6;
  const int l    = tid & 63;
  const int gtid = bid * GTHR + tid;
  cg::grid_group grid = cg::this_grid();

  // ---------------- phase 1: decode (no compaction, per-block counts) ------
  {
    float prob = 0.0f;
    const bool vld = (gtid < N_TOTAL);
    if (vld) {
      int gid = gtid;
      int sc, local;
      if      (gid < 16384) { sc = 0; local = gid;         }
      else if (gid < 20480) { sc = 1; local = gid - 16384; }
      else if (gid < 21504) { sc = 2; local = gid - 20480; }
      else if (gid < 21760) { sc = 3; local = gid - 21504; }
      else if (gid < 21824) { sc = 4; local = gid - 21760; }
      else                  { sc = 5; local = gid - 21824; }

      const int Wd     = 128 >> sc;
      const int stride = 4 << sc;
      const int HW     = Wd * Wd;
      const int x = local & (Wd - 1);
      const int y = local >> (7 - sc);

      const float* cls = P.in.cls[sc];
      const float* reg = P.in.reg[sc];

      float c0 = cls[local];
      float c1 = cls[HW + local];
      float m  = fmaxf(c0, c1);
      float e0 = expf(c0 - m);
      float e1 = expf(c1 - m);
      prob = e1 / (e0 + e1);

      float l0 = reg[local];
      float l1 = reg[HW + local];
      float l2 = reg[2 * HW + local];
      float l3 = reg[3 * HW + local];

      float sF  = (float)stride;
      float pcx = 0.5f * sF + (float)x * sF;
      float pcy = 0.5f * sF + (float)y * sF;
      float pwh = sF * 4.0f;

      float cx = pcx + ((l0 * 0.1f) * pwh);
      float cy = pcy + ((l1 * 0.1f) * pwh);
      float w  = pwh * expf(l2 * 0.2f);
      float h  = pwh * expf(l3 * 0.2f);
      float x1 = cx - w * 0.5f;
      float y1 = cy - h * 0.5f;
      float x2 = x1 + w;
      float y2 = y1 + h;

      P.dx1[gid] = x1; P.dy1[gid] = y1; P.dx2[gid] = x2; P.dy2[gid] = y2;
      P.dsc[gid] = prob;

      // full key array: 0 if not a candidate (suppression only flows down
      // score order; only >FINAL_TH rows are exposed -> restriction exact)
      P.ckey[gid] = (prob > FINAL_TH)
          ? (((unsigned long long)__float_as_uint(prob) << 32) |
             (unsigned int)(~(unsigned int)gid))
          : 0ull;

      P.rank32[gid] = 0u;
      P.cnt[gid]    = 0u;
      if (gid < NA - N_TOTAL) P.cnt[N_TOTAL + gid] = 0u;
    }
    // zero the output (scan scatters kept rows later)
    for (int i = gtid; i < N_TOTAL * 5; i += GBLK * GTHR) P.out[i] = 0.0f;
    // per-block candidate count
    unsigned long long b = __ballot(vld && (prob > FINAL_TH));
    if (l == 0) redsh[wav] = __popcll(b);
    __syncthreads();
    if (tid == 0) {
      int s = 0;
#pragma unroll
      for (int i = 0; i < 16; ++i) s += redsh[i];
      P.blockCnt[bid] = (unsigned)s;
    }
  }
  grid.sync();

  // ---------------- phase 2: rank (count-rank, 688 virtual groups) ---------
  {
    const int vg = bid * 4 + (tid >> 8);          // virtual group id
    if (vg < 86 * NSLICE) {
      const int pgrp  = vg >> 3;
      const int slice = vg & 7;
      const int p     = pgrp * 256 + (tid & 255);
      unsigned long long mykey = (p < N_TOTAL) ? P.ckey[p] : 0ull;
      if (mykey != 0ull) {
        int partial = 0;
        const ulonglong2* k2 = (const ulonglong2*)(P.ckey + slice * SLICE_N);
        for (int j = 0; j < SLICE_N / 2; ++j) {
          ulonglong2 kk = k2[j];
          partial += (kk.x > mykey) ? 1 : 0;
          partial += (kk.y > mykey) ? 1 : 0;
        }
        unsigned int pack = (unsigned int)partial | (1u << 24);
        unsigned int old  = atomicAdd(&P.rank32[p], pack);
        unsigned int newv = old + pack;
        if ((newv >> 24) == NSLICE) {             // last slice scatters
          int r = (int)(newv & 0xFFFFFF);
          unsigned int orig = ~(unsigned int)(mykey & 0xffffffffull);
          P.sx1[r] = P.dx1[orig];
          P.sy1[r] = P.dy1[orig];
          P.sx2[r] = P.dx2[orig];
          P.sy2[r] = P.dy2[orig];
          P.sorig[r] = orig;
        }
      }
    }
  }
  grid.sync();

  // ---------------- phase 3: pairs (LDS-free, triangle wave-tasks) ---------
  {
    const int M = wave_sum_M(P.blockCnt);
    const int W = (M + 63) >> 6;
    const long long T = (long long)W * (W + 1) / 2;
    const int gw = bid * 16 + wav;
    for (long long t = gw; t < T; t += GBLK * 16) {
      // decode t -> (rw, cw): off(r) = r*W - r(r-1)/2, row r has W-r entries
      double D = 2.0 * W + 1.0;
      int rw = (int)((D - sqrt(D * D - 8.0 * (double)t)) * 0.5);
      if (rw > 0 && (long long)rw * W - (long long)rw * (rw - 1) / 2 > t) rw--;
      while ((long long)(rw + 1) * W - (long long)(rw + 1) * rw / 2 <= t) rw++;
      const int cw = rw + (int)(t - ((long long)rw * W - (long long)rw * (rw - 1) / 2));

      // col boxes: lane l holds col cw*64+l
      const int c = (cw << 6) + l;
      const bool cv = (c < M);
      float cbx1 = cv ? P.sx1[c] :  1e30f;
      float cby1 = cv ? P.sy1[c] :  1e30f;
      float cbx2 = cv ? P.sx2[c] : -1e30f;
      float cby2 = cv ? P.sy2[c] : -1e30f;
      float car  = (cbx2 - cbx1 + 1.0f) * (cby2 - cby1 + 1.0f);
      // row boxes: lane l holds row rw*64+l
      const int r = (rw << 6) + l;
      const bool rv = (r < M);
      float ax1 = rv ? P.sx1[r] :  1e30f;
      float ay1 = rv ? P.sy1[r] :  1e30f;
      float ax2 = rv ? P.sx2[r] : -1e30f;
      float ay2 = rv ? P.sy2[r] : -1e30f;
      float aarea = (ax2 - ax1 + 1.0f) * (ay2 - ay1 + 1.0f);

      unsigned long long bits = 0ull;
      for (int cc = 0; cc < 64; ++cc) {
        float qx1 = rl_f(cbx1, cc), qy1 = rl_f(cby1, cc);
        float qx2 = rl_f(cbx2, cc), qy2 = rl_f(cby2, cc);
        float qar = rl_f(car, cc);
        int cg = (cw << 6) + cc;
        float xx1 = fmaxf(ax1, qx1);
        float yy1 = fmaxf(ay1, qy1);
        float xx2 = fminf(ax2, qx2);
        float yy2 = fminf(ay2, qy2);
        float ww = fmaxf(xx2 - xx1 + 1.0f, 0.0f);
        float hh = fmaxf(yy2 - yy1 + 1.0f, 0.0f);
        float inter = ww * hh;
        float iou = inter / (aarea + qar - inter);
        if (cg > r && iou > NMS_TH) bits |= (1ull << cc);
      }
      if (cw == rw)           P.diag[r] = bits;
      else if (cw == rw + 1)  P.offd[r] = bits;
      else if (bits != 0ull) {
        unsigned k = atomicAdd(&P.cnt[r], 1u);
        unsigned b = rowbase_u((unsigned)r) + k;
        P.rlJw[b]   = (unsigned short)cw;
        P.rlBits[b] = bits;
      }
    }
  }
  grid.sync();

  // ---------------- phase 4: scan (block 0 only) ---------------------------
  if (bid == 0) {
    const int M = wave_sum_M(P.blockCnt);
    const int W = (M + 63) >> 6;
    const int g = wav;
    for (int i = tid; i < W_MAX; i += GTHR) { sup[i] = 0ull; kmls[i] = 0ull; }
    block_bar();

    if (g == 0) {
      // -------- scanner wave: readlane scan + direct LDS-atomic carry ------
      unsigned long long rb = (W > 0) ? P.diag[l] : 0ull;
      unsigned long long pv = (W > 1) ? P.offd[l] : 0ull;
      for (int w = 0; w < W; ++w) {
        const int base = w << 6;
        unsigned long long supw = sup[w];        // includes w-1 carry (atomic)
        unsigned long long rowbits = rb;
        unsigned long long pvc = pv;
        {   // prefetch next step's two blocks
          int rn = base + 64 + l;
          rb = (w + 1 < W) ? P.diag[rn] : 0ull;
          pv = (w + 2 < W) ? P.offd[rn] : 0ull;
        }
        unsigned long long nz = __ballot(rowbits != 0ull);
        const int n = min(64, M - base);
        unsigned long long wordmask = (n >= 64) ? ~0ull : ((1ull << n) - 1ull);
        unsigned long long pend = (~supw) & wordmask;
        unsigned long long kept = 0ull;
        unsigned long long act = pend & nz;
        while (act) {                     // iterations = #kept rows w/ bits
          int i = __builtin_ctzll(act);   // uniform
          unsigned long long upto = (2ull << i) - 1ull;
          kept |= pend & upto;
          unsigned long long ri = rl_u64(rowbits, i);   // VALU readlane
          pend &= ~upto;
          pend &= ~ri;
          act = pend & nz;
        }
        kept |= pend;
        if (l == 0) kmls[w] = kept;
        // carry w -> w+1: kept lanes OR their offd bits straight into sup
        if (((kept >> l) & 1ull) && pvc != 0ull && (w + 1 < W))
          atomicOr(&sup[w + 1], pvc);
        block_bar();
      }
    } else {
      // -------- pusher lanes: 960 = 64 rows x 15 slots ---------------------
      const int p = (g - 1) * 64 + l;
      const int jrow = p / 15;
      const int sub  = p % 15;
      unsigned c0, c1, c2, c3;
      unsigned long long b0, b1, b2;
      unsigned j0, j1, j2;
      {
        c0 = (0 < W) ? P.cnt[jrow] : 0u;
        c1 = (1 < W) ? P.cnt[64 + jrow] : 0u;
        c2 = (2 < W) ? P.cnt[128 + jrow] : 0u;
        c3 = (3 < W) ? P.cnt[192 + jrow] : 0u;
        unsigned i;
        i = rowbase_u((unsigned)jrow) + sub;         if (i >= TOT_ENT) i = 0;
        b0 = P.rlBits[i]; j0 = P.rlJw[i];
        i = rowbase_u((unsigned)(64 + jrow)) + sub;  if (i >= TOT_ENT) i = 0;
        b1 = P.rlBits[i]; j1 = P.rlJw[i];
        i = rowbase_u((unsigned)(128 + jrow)) + sub; if (i >= TOT_ENT) i = 0;
        b2 = P.rlBits[i]; j2 = P.rlJw[i];
      }
      for (int w = 0; w < W; ++w) {
        block_bar();
        const unsigned long long km = kmls[w];
        if ((km >> jrow) & 1ull) {
          if (sub < (int)c0) atomicOr(&sup[j0], b0);
          if (c0 > 15u) {                // rare high-degree tail
            unsigned rb_ = rowbase_u((unsigned)(w * 64 + jrow));
            for (int k = sub + 15; k < (int)c0; k += 15) {
              unsigned ii = rb_ + k;
              atomicOr(&sup[P.rlJw[ii]], P.rlBits[ii]);
            }
          }
        }
        c0 = c1; c1 = c2; c2 = c3;
        b0 = b1; j0 = j1; b1 = b2; j1 = j2;
        {
          int w4 = w + 4;
          c3 = (w4 < W) ? P.cnt[w4 * 64 + jrow] : 0u;
          int w3 = w + 3;
          bool ld = (w3 < W) && (sub < (int)c2);
          unsigned i = ld ? (rowbase_u((unsigned)(w3 * 64 + jrow)) + sub) : 0u;
          if (i >= TOT_ENT) i = 0;
          b2 = ld ? P.rlBits[i] : 0ull;
          j2 = ld ? (unsigned)P.rlJw[i] : 0u;
        }
      }
    }
    block_bar();

    // scatter kept rows into the (pre-zeroed) output
    for (int i = tid; i < (W << 6); i += GTHR) {
      if ((kmls[i >> 6] >> (i & 63)) & 1ull) {
        unsigned int orig = P.sorig[i];
        P.out[(size_t)orig * 5 + 0] = P.dx1[orig];
        P.out[(size_t)orig * 5 + 1] = P.dy1[orig];
        P.out[(size_t)orig * 5 + 2] = P.dx2[orig];
        P.out[(size_t)orig * 5 + 3] = P.dy2[orig];
        P.out[(size_t)orig * 5 + 4] = P.dsc[orig];
      }
    }
  }
}

// ======================= fallback kernels (R7 path) =========================
__global__ void decode_kernel(Inputs in,
                              float* __restrict__ dx1, float* __restrict__ dy1,
                              float* __restrict__ dx2, float* __restrict__ dy2,
                              float* __restrict__ dsc,
                              unsigned long long* __restrict__ ckey,
                              unsigned int* __restrict__ Mc,
                              unsigned int* __restrict__ rank32,
                              unsigned int* __restrict__ cnt,
                              float* __restrict__ out) {
#pragma clang fp contract(off)
  int gid = blockIdx.x * blockDim.x + threadIdx.x;
  if (gid >= N_TOTAL) return;
  rank32[gid] = 0u;
  cnt[gid] = 0u;
  if (gid < NA - N_TOTAL) cnt[N_TOTAL + gid] = 0u;
  int sc, local;
  if      (gid < 16384) { sc = 0; local = gid;         }
  else if (gid < 20480) { sc = 1; local = gid - 16384; }
  else if (gid < 21504) { sc = 2; local = gid - 20480; }
  else if (gid < 21760) { sc = 3; local = gid - 21504; }
  else if (gid < 21824) { sc = 4; local = gid - 21760; }
  else                  { sc = 5; local = gid - 21824; }
  const int Wd = 128 >> sc, stride = 4 << sc, HW = Wd * Wd;
  const int x = local & (Wd - 1), y = local >> (7 - sc);
  const float* cls = in.cls[sc];
  const float* reg = in.reg[sc];
  float c0 = cls[local], c1 = cls[HW + local];
  float m  = fmaxf(c0, c1);
  float e0 = expf(c0 - m), e1 = expf(c1 - m);
  float prob = e1 / (e0 + e1);
  float l0 = reg[local], l1 = reg[HW + local];
  float l2 = reg[2 * HW + local], l3 = reg[3 * HW + local];
  float sF  = (float)stride;
  float pcx = 0.5f * sF + (float)x * sF;
  float pcy = 0.5f * sF + (float)y * sF;
  float pwh = sF * 4.0f;
  float cx = pcx + ((l0 * 0.1f) * pwh);
  float cy = pcy + ((l1 * 0.1f) * pwh);
  float w  = pwh * expf(l2 * 0.2f);
  float h  = pwh * expf(l3 * 0.2f);
  float x1 = cx - w * 0.5f, y1 = cy - h * 0.5f;
  float x2 = x1 + w, y2 = y1 + h;
  dx1[gid] = x1; dy1[gid] = y1; dx2[gid] = x2; dy2[gid] = y2; dsc[gid] = prob;
  out[gid * 5 + 0] = 0.0f; out[gid * 5 + 1] = 0.0f; out[gid * 5 + 2] = 0.0f;
  out[gid * 5 + 3] = 0.0f; out[gid * 5 + 4] = 0.0f;
  if (prob > FINAL_TH) {
    unsigned int pos = atomicAdd(Mc, 1u);
    ckey[pos] = ((unsigned long long)__float_as_uint(prob) << 32) |
                (unsigned int)(~(unsigned int)gid);
  }
}

__global__ void __launch_bounds__(256)
rank_kernel(const unsigned long long* __restrict__ ckey,
            const unsigned int* __restrict__ Mc,
            const float* __restrict__ dx1, const float* __restrict__ dy1,
            const float* __restrict__ dx2, const float* __restrict__ dy2,
            float* __restrict__ sx1, float* __restrict__ sy1,
            float* __restrict__ sx2, float* __restrict__ sy2,
            unsigned int* __restrict__ sorig,
            unsigned int* __restrict__ rank32) {
  __shared__ unsigned long long tile[256];
  const unsigned int M = *Mc;
  if (blockIdx.x * 256u >= M) return;
  const int t = (int)threadIdx.x;
  const int p = (int)blockIdx.x * 256 + t;
  unsigned long long mykey = (p < (int)M) ? ckey[p] : 0ull;
  const int S  = (int)((M + NSLICE - 1) / NSLICE);
  const int lo = (int)blockIdx.y * S;
  const int hi = min((int)M, lo + S);
  int partial = 0;
  const int nt = (hi > lo) ? ((hi - lo + 255) >> 8) : 0;
  for (int ti = 0; ti < nt; ++ti) {
    int j = lo + ti * 256 + t;
    tile[t] = (j < hi) ? ckey[j] : 0ull;
    __syncthreads();
#pragma unroll 8
    for (int q = 0; q < 256; ++q) partial += (tile[q] > mykey) ? 1 : 0;
    __syncthreads();
  }
  if (p < (int)M) {
    unsigned int pack = (unsigned int)partial | (1u << 24);
    unsigned int old  = atomicAdd(&rank32[p], pack);
    unsigned int newv = old + pack;
    if ((newv >> 24) == NSLICE) {
      int r = (int)(newv & 0xFFFFFF);
      unsigned int orig = ~(unsigned int)(mykey & 0xffffffffull);
      sx1[r] = dx1[orig]; sy1[r] = dy1[orig];
      sx2[r] = dx2[orig]; sy2[r] = dy2[orig];
      sorig[r] = orig;
    }
  }
}

__global__ void __launch_bounds__(1024)
pairs_kernel(const float* __restrict__ sx1, const float* __restrict__ sy1,
             const float* __restrict__ sx2, const float* __restrict__ sy2,
             const unsigned int* __restrict__ Mc,
             unsigned long long* __restrict__ diag,
             unsigned long long* __restrict__ offd,
             unsigned int* __restrict__ cnt,
             unsigned short* __restrict__ rlJw,
             unsigned long long* __restrict__ rlBits) {
#pragma clang fp contract(off)
  const int M = (int)*Mc;
  const int W = (M + 63) >> 6;
  const int rw = (int)blockIdx.y;
  const int cwg = (int)blockIdx.x << 4;
  if (rw >= W || cwg >= W || cwg + 15 < rw) return;
  const int t = (int)threadIdx.x;
  const int g = t >> 6, l = t & 63;
  const int cw = cwg + g;
  __shared__ float cx1[1024], cy1[1024], cx2[1024], cy2[1024], car[1024];
  {
    int c = (cw << 6) + l;
    if (cw < W && c < M) {
      float a = sx1[c], b = sy1[c], d = sx2[c], e = sy2[c];
      cx1[t] = a; cy1[t] = b; cx2[t] = d; cy2[t] = e;
      car[t] = (d - a + 1.0f) * (e - b + 1.0f);
    }
  }
  __syncthreads();
  if (cw >= W || cw < rw) return;
  const int r = (rw << 6) + l;
  unsigned long long bits = 0ull;
  if (r < M) {
    float ax1 = sx1[r], ay1 = sy1[r], ax2 = sx2[r], ay2 = sy2[r];
    float aarea = (ax2 - ax1 + 1.0f) * (ay2 - ay1 + 1.0f);
    const int cmax = min(64, M - (cw << 6));
    const int sb = g << 6;
    for (int cc = 0; cc < cmax; ++cc) {
      int cg = (cw << 6) + cc;
      if (cg > r) {
        float xx1 = fmaxf(ax1, cx1[sb + cc]);
        float yy1 = fmaxf(ay1, cy1[sb + cc]);
        float xx2 = fminf(ax2, cx2[sb + cc]);
        float yy2 = fminf(ay2, cy2[sb + cc]);
        float ww = fmaxf(xx2 - xx1 + 1.0f, 0.0f);
        float hh = fmaxf(yy2 - yy1 + 1.0f, 0.0f);
        float inter = ww * hh;
        float iou = inter / (aarea + car[sb + cc] - inter);
        if (iou > NMS_TH) bits |= (1ull << cc);
      }
    }
  }
  if (cw == rw)            diag[r] = bits;
  else if (cw == rw + 1)   offd[r] = bits;
  else if (bits != 0ull) {
    unsigned k = atomicAdd(&cnt[r], 1u);
    unsigned b = rowbase_u((unsigned)r) + k;
    rlJw[b]   = (unsigned short)cw;
    rlBits[b] = bits;
  }
}

__global__ void __launch_bounds__(1024)
scan_kernel(const unsigned long long* __restrict__ diag,
            const unsigned long long* __restrict__ offd,
            const unsigned int* __restrict__ cnt,
            const unsigned short* __restrict__ rlJw,
            const unsigned long long* __restrict__ rlBits,
            const unsigned int* __restrict__ sorig,
            const unsigned int* __restrict__ Mc,
            const float* __restrict__ dx1, const float* __restrict__ dy1,
            const float* __restrict__ dx2, const float* __restrict__ dy2,
            const float* __restrict__ dsc,
            float* __restrict__ out) {
  __shared__ unsigned long long sup[W_MAX];
  __shared__ unsigned long long kmls[W_MAX];
  const int t = (int)threadIdx.x;
  const int g = t >> 6, l = t & 63;
  const int M = (int)*Mc;
  const int W = (M + 63) >> 6;
  for (int i = t; i < W_MAX; i += 1024) { sup[i] = 0ull; kmls[i] = 0ull; }
  block_bar();
  if (g == 0) {
    unsigned long long rb = (W > 0) ? diag[l] : 0ull;
    unsigned long long pv = (W > 1) ? offd[l] : 0ull;
    for (int w = 0; w < W; ++w) {
      const int base = w << 6;
      unsigned long long supw = sup[w];
      unsigned long long rowbits = rb;
      unsigned long long pvc = pv;
      {
        int rn = base + 64 + l;
        rb = (w + 1 < W) ? diag[rn] : 0ull;
        pv = (w + 2 < W) ? offd[rn] : 0ull;
      }
      unsigned long long nz = __ballot(rowbits != 0ull);
      const int n = min(64, M - base);
      unsigned long long wordmask = (n >= 64) ? ~0ull : ((1ull << n) - 1ull);
      unsigned long long pend = (~supw) & wordmask;
      unsigned long long kept = 0ull;
      unsigned long long act = pend & nz;
      while (act) {
        int i = __builtin_ctzll(act);
        unsigned long long upto = (2ull << i) - 1ull;
        kept |= pend & upto;
        unsigned long long ri = rl_u64(rowbits, i);
        pend &= ~upto;
        pend &= ~ri;
        act = pend & nz;
      }
      kept |= pend;
      if (l == 0) kmls[w] = kept;
      if (((kept >> l) & 1ull) && pvc != 0ull && (w + 1 < W))
        atomicOr(&sup[w + 1], pvc);
      block_bar();
    }
  } else {
    const int p = (g - 1) * 64 + l;
    const int jrow = p / 15;
    const int sub  = p % 15;
    unsigned c0, c1, c2, c3;
    unsigned long long b0, b1, b2;
    unsigned j0, j1, j2;
    {
      c0 = (0 < W) ? cnt[jrow] : 0u;
      c1 = (1 < W) ? cnt[64 + jrow] : 0u;
      c2 = (2 < W) ? cnt[128 + jrow] : 0u;
      c3 = (3 < W) ? cnt[192 + jrow] : 0u;
      unsigned i;
      i = rowbase_u((unsigned)jrow) + sub;         if (i >= TOT_ENT) i = 0;
      b0 = rlBits[i]; j0 = rlJw[i];
      i = rowbase_u((unsigned)(64 + jrow)) + sub;  if (i >= TOT_ENT) i = 0;
      b1 = rlBits[i]; j1 = rlJw[i];
      i = rowbase_u((unsigned)(128 + jrow)) + sub; if (i >= TOT_ENT) i = 0;
      b2 = rlBits[i]; j2 = rlJw[i];
    }
    for (int w = 0; w < W; ++w) {
      block_bar();
      const unsigned long long km = kmls[w];
      if ((km >> jrow) & 1ull) {
        if (sub < (int)c0) atomicOr(&sup[j0], b0);
        if (c0 > 15u) {
          unsigned rb_ = rowbase_u((unsigned)(w * 64 + jrow));
          for (int k = sub + 15; k < (int)c0; k += 15) {
            unsigned ii = rb_ + k;
            atomicOr(&sup[rlJw[ii]], rlBits[ii]);
          }
        }
      }
      c0 = c1; c1 = c2; c2 = c3;
      b0 = b1; j0 = j1; b1 = b2; j1 = j2;
      {
        int w4 = w + 4;
        c3 = (w4 < W) ? cnt[w4 * 64 + jrow] : 0u;
        int w3 = w + 3;
        bool ld = (w3 < W) && (sub < (int)c2);
        unsigned i = ld ? (rowbase_u((unsigned)(w3 * 64 + jrow)) + sub) : 0u;
        if (i >= TOT_ENT) i = 0;
        b2 = ld ? rlBits[i] : 0ull;
        j2 = ld ? (unsigned)rlJw[i] : 0u;
      }
    }
  }
  block_bar();
  for (int i = t; i < (W << 6); i += 1024) {
    if ((kmls[i >> 6] >> (i & 63)) & 1ull) {
      unsigned int orig = sorig[i];
      out[(size_t)orig * 5 + 0] = dx1[orig];
      out[(size_t)orig * 5 + 1] = dy1[orig];
      out[(size_t)orig * 5 + 2] = dx2[orig];
      out[(size_t)orig * 5 + 3] = dy2[orig];
      out[(size_t)orig * 5 + 4] = dsc[orig];
    }
  }
}

// ---------------------------------------------------------------- launch ----
extern "C" void kernel_launch(void* const* d_in, const int* in_sizes, int n_in,
                              void* d_out, int out_size, void* d_ws, size_t ws_size,
                              hipStream_t stream) {
  (void)in_sizes; (void)n_in; (void)out_size;

  Inputs in;
  for (int i = 0; i < 6; ++i) {
    in.cls[i] = (const float*)d_in[2 * i];
    in.reg[i] = (const float*)d_in[2 * i + 1];
  }

  char* ws = (char*)d_ws;
  size_t o = 0;
  float* dx1 = (float*)(ws + o); o += (size_t)NA * 4;
  float* dy1 = (float*)(ws + o); o += (size_t)NA * 4;
  float* dx2 = (float*)(ws + o); o += (size_t)NA * 4;
  float* dy2 = (float*)(ws + o); o += (size_t)NA * 4;
  float* dsc = (float*)(ws + o); o += (size_t)NA * 4;
  unsigned long long* ckey = (unsigned long long*)(ws + o); o += (size_t)NA * 8;
  float* sx1 = (float*)(ws + o); o += (size_t)NA * 4;
  float* sy1 = (float*)(ws + o); o += (size_t)NA * 4;
  float* sx2 = (float*)(ws + o); o += (size_t)NA * 4;
  float* sy2 = (float*)(ws + o); o += (size_t)NA * 4;
  unsigned int* sorig = (unsigned int*)(ws + o); o += (size_t)NA * 4;
  unsigned int* rank32 = (unsigned int*)(ws + o); o += (size_t)NA * 4;
  unsigned int* cnt = (unsigned int*)(ws + o); o += (size_t)NA * 4;
  unsigned int* Mc = (unsigned int*)(ws + o); o += 64;
  o = (o + 511) & ~(size_t)511;
  unsigned int* blockCnt = (unsigned int*)(ws + o); o += 1024;   // 256 u32, 16B-aligned
  unsigned long long* diag = (unsigned long long*)(ws + o); o += (size_t)NA * 8;
  unsigned long long* offd = (unsigned long long*)(ws + o); o += (size_t)NA * 8;
  unsigned long long* rlBits = (unsigned long long*)(ws + o); o += (size_t)TOT_ENT * 8;
  unsigned short* rlJw = (unsigned short*)(ws + o); o += (size_t)TOT_ENT * 2;
  size_t need = o;                            // ~40 MiB
  const bool fast = (need <= ws_size);

  const int nb = (N_TOTAL + 255) / 256;  // 86

  bool done = false;
  if (fast) {
    Params P;
    P.in = in;
    P.dx1 = dx1; P.dy1 = dy1; P.dx2 = dx2; P.dy2 = dy2; P.dsc = dsc;
    P.ckey = ckey; P.rank32 = rank32; P.cnt = cnt; P.blockCnt = blockCnt;
    P.sx1 = sx1; P.sy1 = sy1; P.sx2 = sx2; P.sy2 = sy2; P.sorig = sorig;
    P.diag = diag; P.offd = offd; P.rlJw = rlJw; P.rlBits = rlBits;
    P.out = (float*)d_out;
    void* args[] = { &P };
    hipError_t e = hipLaunchCooperativeKernel((const void*)fused_kernel,
                                              dim3(GBLK), dim3(GTHR),
                                              args, 0, stream);
    done = (e == hipSuccess);
  }
  if (!done && fast) {
    // coop launch unavailable: R7 multi-kernel fast path
    (void)hipMemsetAsync((void*)Mc, 0, 64, stream);
    decode_kernel<<<nb, 256, 0, stream>>>(in, dx1, dy1, dx2, dy2, dsc, ckey, Mc,
                                          rank32, cnt, (float*)d_out);
    rank_kernel<<<dim3(nb, NSLICE), 256, 0, stream>>>(ckey, Mc, dx1, dy1, dx2, dy2,
                                                      sx1, sy1, sx2, sy2, sorig,
                                                      rank32);
    pairs_kernel<<<dim3(22, W_MAX), 1024, 0, stream>>>(sx1, sy1, sx2, sy2, Mc,
                                                       diag, offd, cnt, rlJw, rlBits);
    scan_kernel<<<1, 1024, 0, stream>>>(diag, offd, cnt, rlJw, rlBits, sorig, Mc,
                                        dx1, dy1, dx2, dy2, dsc, (float*)d_out);
    done = true;
  }
  if (!done) {
    // tiny-ws emergency path: R7 fast chain still fits in ~40MB; if even that
    // fails there is no smaller correct path in this build — run it anyway on
    // the assumption ws >= need (harness has provided >= 57MB historically).
    (void)hipMemsetAsync((void*)Mc, 0, 64, stream);
    decode_kernel<<<nb, 256, 0, stream>>>(in, dx1, dy1, dx2, dy2, dsc, ckey, Mc,
                                          rank32, cnt, (float*)d_out);
    rank_kernel<<<dim3(nb, NSLICE), 256, 0, stream>>>(ckey, Mc, dx1, dy1, dx2, dy2,
                                                      sx1, sy1, sx2, sy2, sorig,
                                                      rank32);
    pairs_kernel<<<dim3(22, W_MAX), 1024, 0, stream>>>(sx1, sy1, sx2, sy2, Mc,
                                                       diag, offd, cnt, rlJw, rlBits);
    scan_kernel<<<1, 1024, 0, stream>>>(diag, offd, cnt, rlJw, rlBits, sorig, Mc,
                                        dx1, dy1, dx2, dy2, dsc, (float*)d_out);
  }
}

// Round 9
// 347.592 us; speedup vs baseline: 1.7046x; 1.7046x over previous
//
#include <hip/hip_runtime.h>
#include <stdint.h>

#define N_TOTAL 21840
#define NA      21888          // N_TOTAL rounded up to multiple of 64
#define W_MAX   342            // ceil(21840/64)
#define TOT_ENT 3753792u       // 64 * (342*343/2)  triangular CSR capacity
#define NMS_TH  0.3f
#define FINAL_TH 0.5f
#define NSLICE  8              // rank range-split factor

struct Inputs { const float* cls[6]; const float* reg[6]; };

// Raw barrier: drains LDS (lgkmcnt) but NOT vmem — prefetched global loads
// stay in flight. Valid when barriers order LDS state only (true in scan:
// all global inputs are read-only there).
__device__ __forceinline__ void block_bar() {
  asm volatile("s_waitcnt lgkmcnt(0)\n\ts_barrier" ::: "memory");
}

// Closed-form CSR row base: row r (sorted pos) owns 342-(r>>6) slots.
__device__ __forceinline__ unsigned rowbase_u(unsigned r) {
  unsigned w = r >> 6, l = r & 63u;
  return 64u * (342u * w - (w * (w - 1u)) / 2u) + l * (342u - w);
}

// VALU-speed cross-lane u64 read (index wave-uniform) — no DS latency.
__device__ __forceinline__ unsigned long long rl_u64(unsigned long long x, int i) {
  unsigned lo = (unsigned)__builtin_amdgcn_readlane((int)(unsigned)(x & 0xffffffffull), i);
  unsigned hi = (unsigned)__builtin_amdgcn_readlane((int)(unsigned)(x >> 32), i);
  return ((unsigned long long)hi << 32) | lo;
}

// ---------------------------------------------------------------- decode ----
__global__ void decode_kernel(Inputs in,
                              float* __restrict__ dx1, float* __restrict__ dy1,
                              float* __restrict__ dx2, float* __restrict__ dy2,
                              float* __restrict__ dsc,
                              unsigned long long* __restrict__ ckey,
                              unsigned int* __restrict__ Mc,
                              unsigned int* __restrict__ rank32,
                              unsigned int* __restrict__ cnt,
                              float* __restrict__ out) {
#pragma clang fp contract(off)
  int gid = blockIdx.x * blockDim.x + threadIdx.x;
  if (gid >= N_TOTAL) return;
  rank32[gid] = 0u;
  cnt[gid] = 0u;
  if (gid < NA - N_TOTAL) cnt[N_TOTAL + gid] = 0u;
  int sc, local;
  if      (gid < 16384) { sc = 0; local = gid;         }
  else if (gid < 20480) { sc = 1; local = gid - 16384; }
  else if (gid < 21504) { sc = 2; local = gid - 20480; }
  else if (gid < 21760) { sc = 3; local = gid - 21504; }
  else if (gid < 21824) { sc = 4; local = gid - 21760; }
  else                  { sc = 5; local = gid - 21824; }
  const int Wd = 128 >> sc, stride = 4 << sc, HW = Wd * Wd;
  const int x = local & (Wd - 1), y = local >> (7 - sc);
  const float* cls = in.cls[sc];
  const float* reg = in.reg[sc];
  float c0 = cls[local], c1 = cls[HW + local];
  float m  = fmaxf(c0, c1);
  float e0 = expf(c0 - m), e1 = expf(c1 - m);
  float prob = e1 / (e0 + e1);
  float l0 = reg[local], l1 = reg[HW + local];
  float l2 = reg[2 * HW + local], l3 = reg[3 * HW + local];
  float sF  = (float)stride;
  float pcx = 0.5f * sF + (float)x * sF;
  float pcy = 0.5f * sF + (float)y * sF;
  float pwh = sF * 4.0f;
  float cx = pcx + ((l0 * 0.1f) * pwh);
  float cy = pcy + ((l1 * 0.1f) * pwh);
  float w  = pwh * expf(l2 * 0.2f);
  float h  = pwh * expf(l3 * 0.2f);
  float x1 = cx - w * 0.5f, y1 = cy - h * 0.5f;
  float x2 = x1 + w, y2 = y1 + h;
  dx1[gid] = x1; dy1[gid] = y1; dx2[gid] = x2; dy2[gid] = y2; dsc[gid] = prob;
  out[gid * 5 + 0] = 0.0f; out[gid * 5 + 1] = 0.0f; out[gid * 5 + 2] = 0.0f;
  out[gid * 5 + 3] = 0.0f; out[gid * 5 + 4] = 0.0f;
  // Only boxes with score > FINAL_TH can affect the output (suppression only
  // flows downward in score order, and only >FINAL_TH rows are exposed).
  if (prob > FINAL_TH) {
    unsigned int pos = atomicAdd(Mc, 1u);
    ckey[pos] = ((unsigned long long)__float_as_uint(prob) << 32) |
                (unsigned int)(~(unsigned int)gid);
  }
}

// ---------------------------------------------------------------- rank ------
// Count-rank with 8-way key-range split; packed atomicAdd join (measured-good
// R7 form — LDS-tiled over the COMPACTED key array).
__global__ void __launch_bounds__(256)
rank_kernel(const unsigned long long* __restrict__ ckey,
            const unsigned int* __restrict__ Mc,
            const float* __restrict__ dx1, const float* __restrict__ dy1,
            const float* __restrict__ dx2, const float* __restrict__ dy2,
            float* __restrict__ sx1, float* __restrict__ sy1,
            float* __restrict__ sx2, float* __restrict__ sy2,
            unsigned int* __restrict__ sorig,
            unsigned int* __restrict__ rank32) {
  __shared__ unsigned long long tile[256];
  const unsigned int M = *Mc;
  if (blockIdx.x * 256u >= M) return;
  const int t = (int)threadIdx.x;
  const int p = (int)blockIdx.x * 256 + t;
  unsigned long long mykey = (p < (int)M) ? ckey[p] : 0ull;
  const int S  = (int)((M + NSLICE - 1) / NSLICE);
  const int lo = (int)blockIdx.y * S;
  const int hi = min((int)M, lo + S);
  int partial = 0;
  const int nt = (hi > lo) ? ((hi - lo + 255) >> 8) : 0;
  for (int ti = 0; ti < nt; ++ti) {
    int j = lo + ti * 256 + t;
    tile[t] = (j < hi) ? ckey[j] : 0ull;
    __syncthreads();
#pragma unroll 8
    for (int q = 0; q < 256; ++q) partial += (tile[q] > mykey) ? 1 : 0;
    __syncthreads();
  }
  if (p < (int)M) {
    unsigned int pack = (unsigned int)partial | (1u << 24);
    unsigned int old  = atomicAdd(&rank32[p], pack);
    unsigned int newv = old + pack;
    if ((newv >> 24) == NSLICE) {
      int r = (int)(newv & 0xFFFFFF);
      unsigned int orig = ~(unsigned int)(mykey & 0xffffffffull);
      sx1[r] = dx1[orig]; sy1[r] = dy1[orig];
      sx2[r] = dx2[orig]; sy2[r] = dy2[orig];
      sorig[r] = orig;
    }
  }
}

// ---------------------------------------------------------------- pairs -----
// Sparse suppression structure (measured-good R7 form):
//   diag[r] = in-word bits; offd[r] = bits vs next word;
//   CSR rows rlJw/rlBits[rowbase(r)+k], k < cnt[r], for cw >= rw+2, bits != 0.
__global__ void __launch_bounds__(1024)
pairs_kernel(const float* __restrict__ sx1, const float* __restrict__ sy1,
             const float* __restrict__ sx2, const float* __restrict__ sy2,
             const unsigned int* __restrict__ Mc,
             unsigned long long* __restrict__ diag,
             unsigned long long* __restrict__ offd,
             unsigned int* __restrict__ cnt,
             unsigned short* __restrict__ rlJw,
             unsigned long long* __restrict__ rlBits) {
#pragma clang fp contract(off)
  const int M = (int)*Mc;
  const int W = (M + 63) >> 6;
  const int rw = (int)blockIdx.y;
  const int cwg = (int)blockIdx.x << 4;
  if (rw >= W || cwg >= W || cwg + 15 < rw) return;
  const int t = (int)threadIdx.x;
  const int g = t >> 6, l = t & 63;
  const int cw = cwg + g;
  __shared__ float cx1[1024], cy1[1024], cx2[1024], cy2[1024], car[1024];
  {
    int c = (cw << 6) + l;
    if (cw < W && c < M) {
      float a = sx1[c], b = sy1[c], d = sx2[c], e = sy2[c];
      cx1[t] = a; cy1[t] = b; cx2[t] = d; cy2[t] = e;
      car[t] = (d - a + 1.0f) * (e - b + 1.0f);
    }
  }
  __syncthreads();
  if (cw >= W || cw < rw) return;
  const int r = (rw << 6) + l;
  unsigned long long bits = 0ull;
  if (r < M) {
    float ax1 = sx1[r], ay1 = sy1[r], ax2 = sx2[r], ay2 = sy2[r];
    float aarea = (ax2 - ax1 + 1.0f) * (ay2 - ay1 + 1.0f);
    const int cmax = min(64, M - (cw << 6));
    const int sb = g << 6;
    for (int cc = 0; cc < cmax; ++cc) {
      int cg = (cw << 6) + cc;
      if (cg > r) {
        float xx1 = fmaxf(ax1, cx1[sb + cc]);
        float yy1 = fmaxf(ay1, cy1[sb + cc]);
        float xx2 = fminf(ax2, cx2[sb + cc]);
        float yy2 = fminf(ay2, cy2[sb + cc]);
        float ww = fmaxf(xx2 - xx1 + 1.0f, 0.0f);
        float hh = fmaxf(yy2 - yy1 + 1.0f, 0.0f);
        float inter = ww * hh;
        float iou = inter / (aarea + car[sb + cc] - inter);
        if (iou > NMS_TH) bits |= (1ull << cc);
      }
    }
  }
  if (cw == rw)            diag[r] = bits;
  else if (cw == rw + 1)   offd[r] = bits;
  else if (bits != 0ull) {
    unsigned k = atomicAdd(&cnt[r], 1u);
    unsigned b = rowbase_u((unsigned)r) + k;
    rlJw[b]   = (unsigned short)cw;
    rlBits[b] = bits;
  }
}

// ---------------------------------------------------------------- scan ------
// Single-block greedy scan over the sparse structure. Scanner wave: readlane
// scan (no DS), carry w->w+1 via direct LDS atomicOr (kills the 12-dep
// ds_bpermute chain that dominated R7), 2-step-ahead diag/offd prefetch
// (covers cross-XCD L2 latency). Pushers: CSR entries, arithmetic addresses,
// deep predicated prefetch. ONE barrier per step.
// Barrier pairing: scanner work(w) in [B(w),B(w+1)]; pusher work(w) in
// [B(w+1),B(w+2)] writes only sup[>=w+2]; scanner reads sup[j] in [B(j),B(j+1)].
__global__ void __launch_bounds__(1024)
scan_kernel(const unsigned long long* __restrict__ diag,
            const unsigned long long* __restrict__ offd,
            const unsigned int* __restrict__ cnt,
            const unsigned short* __restrict__ rlJw,
            const unsigned long long* __restrict__ rlBits,
            const unsigned int* __restrict__ sorig,
            const unsigned int* __restrict__ Mc,
            const float* __restrict__ dx1, const float* __restrict__ dy1,
            const float* __restrict__ dx2, const float* __restrict__ dy2,
            const float* __restrict__ dsc,
            float* __restrict__ out) {
  __shared__ unsigned long long sup[W_MAX];
  __shared__ unsigned long long kmls[W_MAX];
  const int t = (int)threadIdx.x;
  const int g = t >> 6, l = t & 63;
  const int M = (int)*Mc;
  const int W = (M + 63) >> 6;
  for (int i = t; i < W_MAX; i += 1024) { sup[i] = 0ull; kmls[i] = 0ull; }
  block_bar();

  if (g == 0) {
    // -------- scanner wave: 2-deep prefetch + readlane + LDS-atomic carry --
    unsigned long long rb0 = (W > 0) ? diag[l] : 0ull;        // word w rows
    unsigned long long rb1 = (W > 1) ? diag[64 + l] : 0ull;   // word w+1 rows
    unsigned long long pv0 = (W > 1) ? offd[l] : 0ull;        // w -> w+1 bits
    unsigned long long pv1 = (W > 2) ? offd[64 + l] : 0ull;   // w+1 -> w+2
    for (int w = 0; w < W; ++w) {
      const int base = w << 6;
      unsigned long long supw = sup[w];        // includes w-1 carry
      unsigned long long rowbits = rb0;
      unsigned long long pvc = pv0;
      rb0 = rb1; pv0 = pv1;
      {   // issue loads for word w+2 (consumed two steps from now)
        int rn = base + 128 + l;
        rb1 = (w + 2 < W) ? diag[rn] : 0ull;
        pv1 = (w + 3 < W) ? offd[rn] : 0ull;
      }
      unsigned long long nz = __ballot(rowbits != 0ull);
      const int n = min(64, M - base);
      unsigned long long wordmask = (n >= 64) ? ~0ull : ((1ull << n) - 1ull);
      unsigned long long pend = (~supw) & wordmask;
      unsigned long long kept = 0ull;
      unsigned long long act = pend & nz;
      while (act) {                     // iterations = #kept rows w/ bits
        int i = __builtin_ctzll(act);   // uniform
        unsigned long long upto = (2ull << i) - 1ull;
        kept |= pend & upto;
        unsigned long long ri = rl_u64(rowbits, i);   // VALU readlane
        pend &= ~upto;
        pend &= ~ri;
        act = pend & nz;
      }
      kept |= pend;
      if (l == 0) kmls[w] = kept;
      // carry w -> w+1: kept lanes OR their offd bits straight into sup
      if (((kept >> l) & 1ull) && pvc != 0ull && (w + 1 < W))
        atomicOr(&sup[w + 1], pvc);
      block_bar();
    }
  } else {
    // -------- pusher lanes: 960 = 64 rows x 15 slots -----------------------
    const int p = (g - 1) * 64 + l;
    const int jrow = p / 15;
    const int sub  = p % 15;
    unsigned c0, c1, c2, c3;
    unsigned long long b0, b1, b2;
    unsigned j0, j1, j2;
    {
      c0 = (0 < W) ? cnt[jrow] : 0u;
      c1 = (1 < W) ? cnt[64 + jrow] : 0u;
      c2 = (2 < W) ? cnt[128 + jrow] : 0u;
      c3 = (3 < W) ? cnt[192 + jrow] : 0u;
      unsigned i;
      i = rowbase_u((unsigned)jrow) + sub;         if (i >= TOT_ENT) i = 0;
      b0 = rlBits[i]; j0 = rlJw[i];
      i = rowbase_u((unsigned)(64 + jrow)) + sub;  if (i >= TOT_ENT) i = 0;
      b1 = rlBits[i]; j1 = rlJw[i];
      i = rowbase_u((unsigned)(128 + jrow)) + sub; if (i >= TOT_ENT) i = 0;
      b2 = rlBits[i]; j2 = rlJw[i];
    }
    for (int w = 0; w < W; ++w) {
      block_bar();
      const unsigned long long km = kmls[w];
      if ((km >> jrow) & 1ull) {
        if (sub < (int)c0) atomicOr(&sup[j0], b0);
        if (c0 > 15u) {                // rare high-degree tail
          unsigned rb_ = rowbase_u((unsigned)(w * 64 + jrow));
          for (int k = sub + 15; k < (int)c0; k += 15) {
            unsigned ii = rb_ + k;
            atomicOr(&sup[rlJw[ii]], rlBits[ii]);
          }
        }
      }
      c0 = c1; c1 = c2; c2 = c3;
      b0 = b1; j0 = j1; b1 = b2; j1 = j2;
      {
        int w4 = w + 4;
        c3 = (w4 < W) ? cnt[w4 * 64 + jrow] : 0u;
        int w3 = w + 3;
        bool ld = (w3 < W) && (sub < (int)c2);
        unsigned i = ld ? (rowbase_u((unsigned)(w3 * 64 + jrow)) + sub) : 0u;
        if (i >= TOT_ENT) i = 0;
        b2 = ld ? rlBits[i] : 0ull;
        j2 = ld ? (unsigned)rlJw[i] : 0u;
      }
    }
  }
  block_bar();

  // scatter kept rows into the (pre-zeroed) output
  for (int i = t; i < (W << 6); i += 1024) {
    if ((kmls[i >> 6] >> (i & 63)) & 1ull) {
      unsigned int orig = sorig[i];
      out[(size_t)orig * 5 + 0] = dx1[orig];
      out[(size_t)orig * 5 + 1] = dy1[orig];
      out[(size_t)orig * 5 + 2] = dx2[orig];
      out[(size_t)orig * 5 + 3] = dy2[orig];
      out[(size_t)orig * 5 + 4] = dsc[orig];
    }
  }
}

// ---------------------------------------------------------------- launch ----
extern "C" void kernel_launch(void* const* d_in, const int* in_sizes, int n_in,
                              void* d_out, int out_size, void* d_ws, size_t ws_size,
                              hipStream_t stream) {
  (void)in_sizes; (void)n_in; (void)out_size; (void)ws_size;

  Inputs in;
  for (int i = 0; i < 6; ++i) {
    in.cls[i] = (const float*)d_in[2 * i];
    in.reg[i] = (const float*)d_in[2 * i + 1];
  }

  char* ws = (char*)d_ws;
  size_t o = 0;
  float* dx1 = (float*)(ws + o); o += (size_t)NA * 4;
  float* dy1 = (float*)(ws + o); o += (size_t)NA * 4;
  float* dx2 = (float*)(ws + o); o += (size_t)NA * 4;
  float* dy2 = (float*)(ws + o); o += (size_t)NA * 4;
  float* dsc = (float*)(ws + o); o += (size_t)NA * 4;
  unsigned long long* ckey = (unsigned long long*)(ws + o); o += (size_t)NA * 8;
  float* sx1 = (float*)(ws + o); o += (size_t)NA * 4;
  float* sy1 = (float*)(ws + o); o += (size_t)NA * 4;
  float* sx2 = (float*)(ws + o); o += (size_t)NA * 4;
  float* sy2 = (float*)(ws + o); o += (size_t)NA * 4;
  unsigned int* sorig = (unsigned int*)(ws + o); o += (size_t)NA * 4;
  unsigned int* rank32 = (unsigned int*)(ws + o); o += (size_t)NA * 4;
  unsigned int* cnt = (unsigned int*)(ws + o); o += (size_t)NA * 4;
  unsigned int* Mc = (unsigned int*)(ws + o); o += 64;
  o = (o + 511) & ~(size_t)511;
  unsigned long long* diag = (unsigned long long*)(ws + o); o += (size_t)NA * 8;
  unsigned long long* offd = (unsigned long long*)(ws + o); o += (size_t)NA * 8;
  unsigned long long* rlBits = (unsigned long long*)(ws + o); o += (size_t)TOT_ENT * 8;
  unsigned short* rlJw = (unsigned short*)(ws + o); o += (size_t)TOT_ENT * 2;

  const int nb = (N_TOTAL + 255) / 256;  // 86

  (void)hipMemsetAsync((void*)Mc, 0, 64, stream);
  decode_kernel<<<nb, 256, 0, stream>>>(in, dx1, dy1, dx2, dy2, dsc, ckey, Mc,
                                        rank32, cnt, (float*)d_out);
  rank_kernel<<<dim3(nb, NSLICE), 256, 0, stream>>>(ckey, Mc, dx1, dy1, dx2, dy2,
                                                    sx1, sy1, sx2, sy2, sorig,
                                                    rank32);
  pairs_kernel<<<dim3(22, W_MAX), 1024, 0, stream>>>(sx1, sy1, sx2, sy2, Mc,
                                                     diag, offd, cnt, rlJw, rlBits);
  scan_kernel<<<1, 1024, 0, stream>>>(diag, offd, cnt, rlJw, rlBits, sorig, Mc,
                                      dx1, dy1, dx2, dy2, dsc, (float*)d_out);
}